// Round 1
// baseline (1678.820 us; speedup 1.0000x reference)
//
#include <hip/hip_runtime.h>
#include <math.h>

#define LRELU(v) ((v) > 0.0f ? (v) : 0.02f * (v))

// ---------------------------------------------------------------------------
// Kernel 1: second-hop graph layer. One block (256 thr) per (b, n1) pair.
// S=32, D=30 (padded to 32), J=3D=90 (padded to 96).
// result[d] = ob[d] + sum_j obar[j]*ow[d][j],
//   obar[h*5+e] = sum_t abar[h][t]*v[t][h][e],  abar[h][t] = mean_s att[h][s][t]
// ---------------------------------------------------------------------------
__global__ __launch_bounds__(256, 2) void gl2_kernel(
    const float* __restrict__ x2,
    const float* __restrict__ lw, const float* __restrict__ lb,
    const float* __restrict__ iw, const float* __restrict__ ib,
    const float* __restrict__ ow, const float* __restrict__ ob,
    float* __restrict__ h1out)
{
    __shared__ float w_lw[32][31];   // lw[d][k], rows 30..31 zero
    __shared__ float w_lb[32];
    __shared__ float w_iw[96][31];   // iw[j][d], rows 90..95 zero
    __shared__ float w_ib[96];
    __shared__ float w_ow[30][31];   // ow[d][j]
    __shared__ float w_ob[32];
    __shared__ float xb[32][33];     // x[s][k], then y[s][d] in place (d<32)
    __shared__ float qkvb[32][97];   // qkv[s][j] (j<96)
    __shared__ float att[192][33];   // att[(h*32+s)][t], normalized
    __shared__ float abar[6][32];
    __shared__ float obar[32];

    const int tid = threadIdx.x;
    const int pair = blockIdx.x;

    // ---- zero padded weight arrays, then fill ----
    for (int i = tid; i < 32 * 31; i += 256) (&w_lw[0][0])[i] = 0.0f;
    for (int i = tid; i < 96 * 31; i += 256) (&w_iw[0][0])[i] = 0.0f;
    if (tid < 32) w_lb[tid] = 0.0f;
    if (tid < 96) w_ib[tid] = 0.0f;
    __syncthreads();
    for (int i = tid; i < 900;  i += 256) w_lw[i / 30][i % 30] = lw[i];
    for (int i = tid; i < 2700; i += 256) w_iw[i / 30][i % 30] = iw[i];
    for (int i = tid; i < 900;  i += 256) w_ow[i / 30][i % 30] = ow[i];
    if (tid < 30) { w_lb[tid] = lb[tid]; w_ob[tid] = ob[tid]; }
    if (tid < 90) w_ib[tid] = ib[tid];
    for (int i = tid; i < 960; i += 256)
        xb[i / 30][i % 30] = x2[(size_t)pair * 960 + i];
    __syncthreads();

    // ---- Phase 1: y = LReLU(x @ lw^T + lb), 32x32 outputs, 2s x 2d tile ----
    {
        const int sp = tid >> 4;          // 0..15
        const int g  = tid & 15;          // 0..15
        const int s0 = sp * 2;
        const int d0 = g, d1 = g + 16;
        float a00 = w_lb[d0], a01 = w_lb[d1];
        float a10 = w_lb[d0], a11 = w_lb[d1];
        #pragma unroll
        for (int k = 0; k < 30; ++k) {
            float x0 = xb[s0][k], x1 = xb[s0 + 1][k];
            float w0 = w_lw[d0][k], w1 = w_lw[d1][k];
            a00 = fmaf(x0, w0, a00); a01 = fmaf(x0, w1, a01);
            a10 = fmaf(x1, w0, a10); a11 = fmaf(x1, w1, a11);
        }
        a00 = LRELU(a00); a01 = LRELU(a01);
        a10 = LRELU(a10); a11 = LRELU(a11);
        __syncthreads();                  // all reads of x done before overwrite
        xb[s0][d0] = a00; xb[s0][d1] = a01;
        xb[s0 + 1][d0] = a10; xb[s0 + 1][d1] = a11;
    }
    __syncthreads();

    // ---- Phase 2: qkv = y @ iw^T + ib, 32x96 outputs, 4s x 3j tile ----
    {
        const int sg = tid >> 5;          // 0..7
        const int jg = tid & 31;          // 0..31
        const int s0 = sg * 4;
        float acc[4][3];
        #pragma unroll
        for (int i = 0; i < 4; ++i) {
            acc[i][0] = w_ib[jg]; acc[i][1] = w_ib[jg + 32]; acc[i][2] = w_ib[jg + 64];
        }
        #pragma unroll
        for (int d = 0; d < 30; ++d) {    // y cols 30,31 are zero; skip
            float w0 = w_iw[jg][d], w1 = w_iw[jg + 32][d], w2 = w_iw[jg + 64][d];
            #pragma unroll
            for (int i = 0; i < 4; ++i) {
                float yv = xb[s0 + i][d];
                acc[i][0] = fmaf(yv, w0, acc[i][0]);
                acc[i][1] = fmaf(yv, w1, acc[i][1]);
                acc[i][2] = fmaf(yv, w2, acc[i][2]);
            }
        }
        #pragma unroll
        for (int i = 0; i < 4; ++i) {
            qkvb[s0 + i][jg]      = acc[i][0];
            qkvb[s0 + i][jg + 32] = acc[i][1];
            qkvb[s0 + i][jg + 64] = acc[i][2];
        }
    }
    __syncthreads();

    // ---- Phase 3: scores row (h,s) -> softmax -> att, one row per thread ----
    if (tid < 192) {
        const int h = tid >> 5, s = tid & 31;
        const float rs5 = 0.44721359549995793f;  // 1/sqrt(5)
        const int cq = h * 5, ck = 30 + h * 5;
        float q0 = qkvb[s][cq], q1 = qkvb[s][cq + 1], q2 = qkvb[s][cq + 2];
        float q3 = qkvb[s][cq + 3], q4 = qkvb[s][cq + 4];
        float sc[32];
        #pragma unroll
        for (int t = 0; t < 32; ++t) {
            float d0 = q0 * qkvb[t][ck] + q1 * qkvb[t][ck + 1];
            float d1 = q2 * qkvb[t][ck + 2] + q3 * qkvb[t][ck + 3];
            sc[t] = (d0 + d1 + q4 * qkvb[t][ck + 4]) * rs5;
        }
        float m = sc[0];
        #pragma unroll
        for (int t = 1; t < 32; ++t) m = fmaxf(m, sc[t]);
        float Z = 0.0f;
        #pragma unroll
        for (int t = 0; t < 32; ++t) { sc[t] = __expf(sc[t] - m); Z += sc[t]; }
        float rZ = 1.0f / Z;
        #pragma unroll
        for (int t = 0; t < 32; ++t) att[tid][t] = sc[t] * rZ;
    }
    __syncthreads();

    // ---- Phase 4: abar[h][t] = mean_s att ----
    if (tid < 192) {
        const int h = tid >> 5, t = tid & 31;
        float sum = 0.0f;
        #pragma unroll
        for (int s = 0; s < 32; ++s) sum += att[h * 32 + s][t];
        abar[h][t] = sum * (1.0f / 32.0f);
    }
    __syncthreads();

    // ---- Phase 5: obar[h*5+e] = sum_t abar[h][t] * v[t][h][e] ----
    if (tid < 30) {
        const int h = tid / 5, e = tid % 5;
        const int cv = 60 + h * 5 + e;
        float acc = 0.0f;
        #pragma unroll
        for (int t = 0; t < 32; ++t) acc = fmaf(abar[h][t], qkvb[t][cv], acc);
        obar[tid] = acc;
    }
    __syncthreads();

    // ---- Phase 6: result = obar @ ow^T + ob -> h1out ----
    if (tid < 30) {
        float r = w_ob[tid];
        #pragma unroll
        for (int j = 0; j < 30; ++j) r = fmaf(obar[j], w_ow[tid][j], r);
        h1out[(size_t)pair * 30 + tid] = r;
    }
}

// ---------------------------------------------------------------------------
// Kernel 2: first-hop graph layer (S=17: 16 h1 rows + self_feat) + MLP + softmax.
// One block (256 thr) per node b. MLP weights read straight from global (L1-hot).
// ---------------------------------------------------------------------------
__global__ __launch_bounds__(256, 2) void gl1_mlp_kernel(
    const float* __restrict__ h1, const float* __restrict__ self_feat,
    const float* __restrict__ lw, const float* __restrict__ lb,
    const float* __restrict__ iw, const float* __restrict__ ib,
    const float* __restrict__ ow, const float* __restrict__ ob,
    const float* __restrict__ cw1, const float* __restrict__ cb1,
    const float* __restrict__ cw2, const float* __restrict__ cb2,
    const float* __restrict__ cw3, const float* __restrict__ cb3,
    float* __restrict__ out)
{
    __shared__ float w_lw[32][31];
    __shared__ float w_lb[32];
    __shared__ float w_iw[96][31];
    __shared__ float w_ib[96];
    __shared__ float w_ow[30][31];
    __shared__ float w_ob[32];
    __shared__ float xb[17][33];     // seq rows, then y in place
    __shared__ float qkvb[17][97];
    __shared__ float att[102][19];
    __shared__ float abar[6][19];
    __shared__ float obar[32];
    __shared__ float emb[32];
    __shared__ float hb1[64];
    __shared__ float hb2[64];
    __shared__ float lg[2];

    const int tid = threadIdx.x;
    const int b = blockIdx.x;

    for (int i = tid; i < 32 * 31; i += 256) (&w_lw[0][0])[i] = 0.0f;
    for (int i = tid; i < 96 * 31; i += 256) (&w_iw[0][0])[i] = 0.0f;
    if (tid < 32) w_lb[tid] = 0.0f;
    if (tid < 96) w_ib[tid] = 0.0f;
    __syncthreads();
    for (int i = tid; i < 900;  i += 256) w_lw[i / 30][i % 30] = lw[i];
    for (int i = tid; i < 2700; i += 256) w_iw[i / 30][i % 30] = iw[i];
    for (int i = tid; i < 900;  i += 256) w_ow[i / 30][i % 30] = ow[i];
    if (tid < 30) { w_lb[tid] = lb[tid]; w_ob[tid] = ob[tid]; }
    if (tid < 90) w_ib[tid] = ib[tid];
    for (int i = tid; i < 480; i += 256)
        xb[i / 30][i % 30] = h1[(size_t)b * 480 + i];
    if (tid < 30) xb[16][tid] = self_feat[(size_t)b * 30 + tid];
    __syncthreads();

    // ---- Phase 1: y = LReLU(x @ lw^T + lb), 17x32 = 544 outputs, in place ----
    {
        auto compY = [&](int idx) -> float {
            int s = idx >> 5, d = idx & 31;
            float a = w_lb[d];
            #pragma unroll
            for (int k = 0; k < 30; ++k) a = fmaf(xb[s][k], w_lw[d][k], a);
            return LRELU(a);
        };
        float y0 = compY(tid);
        float y1 = (tid + 256 < 544) ? compY(tid + 256) : 0.0f;
        bool has2 = (tid + 512 < 544);
        float y2 = has2 ? compY(tid + 512) : 0.0f;
        __syncthreads();
        { int s = tid >> 5, d = tid & 31; xb[s][d] = y0; }
        if (tid + 256 < 544) { int idx = tid + 256; xb[idx >> 5][idx & 31] = y1; }
        if (has2) { int idx = tid + 512; xb[idx >> 5][idx & 31] = y2; }
    }
    __syncthreads();

    // ---- Phase 2: qkv = y @ iw^T + ib, 17x96 = 1632 outputs ----
    for (int idx = tid; idx < 17 * 96; idx += 256) {
        int s = idx / 96, j = idx % 96;
        float a = w_ib[j];
        #pragma unroll
        for (int d = 0; d < 30; ++d) a = fmaf(xb[s][d], w_iw[j][d], a);
        qkvb[s][j] = a;
    }
    __syncthreads();

    // ---- Phase 3: softmax rows (h,s), 102 rows ----
    if (tid < 102) {
        const int h = tid / 17, s = tid % 17;
        const float rs5 = 0.44721359549995793f;
        const int cq = h * 5, ck = 30 + h * 5;
        float q0 = qkvb[s][cq], q1 = qkvb[s][cq + 1], q2 = qkvb[s][cq + 2];
        float q3 = qkvb[s][cq + 3], q4 = qkvb[s][cq + 4];
        float sc[17];
        #pragma unroll
        for (int t = 0; t < 17; ++t) {
            float d0 = q0 * qkvb[t][ck] + q1 * qkvb[t][ck + 1];
            float d1 = q2 * qkvb[t][ck + 2] + q3 * qkvb[t][ck + 3];
            sc[t] = (d0 + d1 + q4 * qkvb[t][ck + 4]) * rs5;
        }
        float m = sc[0];
        #pragma unroll
        for (int t = 1; t < 17; ++t) m = fmaxf(m, sc[t]);
        float Z = 0.0f;
        #pragma unroll
        for (int t = 0; t < 17; ++t) { sc[t] = __expf(sc[t] - m); Z += sc[t]; }
        float rZ = 1.0f / Z;
        #pragma unroll
        for (int t = 0; t < 17; ++t) att[tid][t] = sc[t] * rZ;
    }
    __syncthreads();

    // ---- Phase 4: abar ----
    if (tid < 102) {
        const int h = tid / 17, t = tid % 17;
        float sum = 0.0f;
        #pragma unroll
        for (int s = 0; s < 17; ++s) sum += att[h * 17 + s][t];
        abar[h][t] = sum * (1.0f / 17.0f);
    }
    __syncthreads();

    // ---- Phase 5: obar ----
    if (tid < 30) {
        const int h = tid / 5, e = tid % 5;
        const int cv = 60 + h * 5 + e;
        float acc = 0.0f;
        #pragma unroll
        for (int t = 0; t < 17; ++t) acc = fmaf(abar[h][t], qkvb[t][cv], acc);
        obar[tid] = acc;
    }
    __syncthreads();

    // ---- Phase 6: emb = obar @ ow^T + ob ----
    if (tid < 30) {
        float r = w_ob[tid];
        #pragma unroll
        for (int j = 0; j < 30; ++j) r = fmaf(obar[j], w_ow[tid][j], r);
        emb[tid] = r;
    }
    __syncthreads();

    // ---- MLP: 30 -> 64 -> 64 -> 2, then 2-class softmax ----
    if (tid < 64) {
        float a = cb1[tid];
        #pragma unroll
        for (int k = 0; k < 30; ++k) a = fmaf(emb[k], cw1[tid * 30 + k], a);
        hb1[tid] = LRELU(a);
    }
    __syncthreads();
    if (tid < 64) {
        float a = cb2[tid];
        #pragma unroll
        for (int k = 0; k < 64; ++k) a = fmaf(hb1[k], cw2[tid * 64 + k], a);
        hb2[tid] = LRELU(a);
    }
    __syncthreads();
    if (tid < 2) {
        float a = cb3[tid];
        #pragma unroll
        for (int k = 0; k < 64; ++k) a = fmaf(hb2[k], cw3[tid * 64 + k], a);
        lg[tid] = a;
    }
    __syncthreads();
    if (tid < 2) {
        float m = fmaxf(lg[0], lg[1]);
        float e0 = __expf(lg[0] - m), e1 = __expf(lg[1] - m);
        float p = ((tid == 0) ? e0 : e1) / (e0 + e1);
        out[(size_t)b * 2 + tid] = p;
    }
}

extern "C" void kernel_launch(void* const* d_in, const int* in_sizes, int n_in,
                              void* d_out, int out_size, void* d_ws, size_t ws_size,
                              hipStream_t stream)
{
    const float* x2        = (const float*)d_in[0];
    const float* self_feat = (const float*)d_in[1];
    const float* lin_w2 = (const float*)d_in[2];
    const float* lin_b2 = (const float*)d_in[3];
    const float* in_w2  = (const float*)d_in[4];
    const float* in_b2  = (const float*)d_in[5];
    const float* out_w2 = (const float*)d_in[6];
    const float* out_b2 = (const float*)d_in[7];
    const float* lin_w1 = (const float*)d_in[8];
    const float* lin_b1 = (const float*)d_in[9];
    const float* in_w1  = (const float*)d_in[10];
    const float* in_b1  = (const float*)d_in[11];
    const float* out_w1 = (const float*)d_in[12];
    const float* out_b1 = (const float*)d_in[13];
    const float* cw1 = (const float*)d_in[14];
    const float* cb1 = (const float*)d_in[15];
    const float* cw2 = (const float*)d_in[16];
    const float* cb2 = (const float*)d_in[17];
    const float* cw3 = (const float*)d_in[18];
    const float* cb3 = (const float*)d_in[19];
    float* outp = (float*)d_out;

    float* h1 = (float*)d_ws;   // 65536 * 30 floats = 7.86 MB

    gl2_kernel<<<4096 * 16, 256, 0, stream>>>(
        x2, lin_w2, lin_b2, in_w2, in_b2, out_w2, out_b2, h1);

    gl1_mlp_kernel<<<4096, 256, 0, stream>>>(
        h1, self_feat, lin_w1, lin_b1, in_w1, in_b1, out_w1, out_b1,
        cw1, cb1, cw2, cb2, cw3, cb3, outp);
}

// Round 2
// 660.571 us; speedup vs baseline: 2.5415x; 2.5415x over previous
//
#include <hip/hip_runtime.h>
#include <math.h>

#define LRELU(v) ((v) > 0.0f ? (v) : 0.02f * (v))

typedef __attribute__((ext_vector_type(8))) short  short8;   // 8 bf16 in 4 VGPRs
typedef __attribute__((ext_vector_type(4))) float  f32x4;
typedef _Float16 half_t;
typedef __attribute__((ext_vector_type(8))) _Float16 half8;

__device__ inline short f2bf(float f) {
    unsigned u = __builtin_bit_cast(unsigned, f);
    unsigned r = (u + 0x7FFFu + ((u >> 16) & 1u)) >> 16;   // RNE
    return (short)r;
}

#define PAIRS 8

// ---------------------------------------------------------------------------
// Kernel 1: second-hop graph layer, MFMA edition.
// One block (256 thr) processes PAIRS consecutive (b,n1) pairs.
// P1/P2 via mfma_f32_16x16x32_bf16 with weights resident in register B-frags.
// Attention (scores/softmax/abar/PV/out-proj) via fp32 VALU with fp16 q/k LDS.
// ---------------------------------------------------------------------------
__global__ __launch_bounds__(256, 4) void gl2_kernel(
    const float* __restrict__ x2,
    const float* __restrict__ lw, const float* __restrict__ lb,
    const float* __restrict__ iw, const float* __restrict__ ib,
    const float* __restrict__ ow, const float* __restrict__ ob,
    float* __restrict__ h1out)
{
    __shared__ short  y_lds[32][40];      // y in bf16, rows padded to 40 (80 B)
    __shared__ half_t q16p[32][48];       // q fp16: [s][h*8+e], cols h*8+5..7 stay 0
    __shared__ half_t kT16[6][5][32];     // k fp16: [h][e][t]
    __shared__ float  vT[6][5][36];       // v fp32: [h][e][t], padded row 36
    __shared__ float  att[192][33];       // normalized att * 1/32, stride 33
    __shared__ float  abar[6][32];
    __shared__ float  obar[32];

    const int tid  = threadIdx.x;
    const int lane = tid & 63;
    const int w    = tid >> 6;           // wave 0..3
    const int l15  = lane & 15;
    const int lq   = lane >> 4;          // quad 0..3

    // ---- once-per-block init: zero q16p (cols 5..7 of each head stay zero) ----
    for (int i = tid; i < (32 * 48) / 2; i += 256) ((int*)q16p)[i] = 0;
    if (tid < 2) obar[30 + tid] = 0.0f;

    // ---- persistent register fragments (loaded once per block) ----
    // P1: y = x @ lw^T. Tile (si,di) per wave: si=w>>1, di=w&1.
    // B-frag holds B[k][d] = lw[d][k]: lane d = 16*di + l15, k-chunk = lq*8.
    const int di = w & 1, si = w >> 1;
    short8 blw;
    float  lbv;
    {
        int d = di * 16 + l15;
        #pragma unroll
        for (int i = 0; i < 8; ++i) {
            int k = lq * 8 + i;
            float v = (d < 30 && k < 30) ? lw[d * 30 + k] : 0.0f;
            blw[i] = f2bf(v);
        }
        lbv = (d < 30) ? lb[d] : 0.0f;
    }
    // P2: qkv = y @ iw^T. Wave w owns tiles T=3w..3w+2 (T = jt*2 + si_).
    // Needs 2 B-frags: jtA = (3w)>>1, jtB = (3w+2)>>1.
    const int jtA = (3 * w) >> 1;
    const int jtB = (3 * w + 2) >> 1;
    short8 biwA, biwB;
    float  ibvA, ibvB;
    {
        int jA = jtA * 16 + l15, jB = jtB * 16 + l15;
        #pragma unroll
        for (int i = 0; i < 8; ++i) {
            int k = lq * 8 + i;
            biwA[i] = f2bf((jA < 90 && k < 30) ? iw[jA * 30 + k] : 0.0f);
            biwB[i] = f2bf((jB < 90 && k < 30) ? iw[jB * 30 + k] : 0.0f);
        }
        ibvA = (jA < 90) ? ib[jA] : 0.0f;
        ibvB = (jB < 90) ? ib[jB] : 0.0f;
    }
    __syncthreads();

    for (int p = 0; p < PAIRS; ++p) {
        const long pair = (long)blockIdx.x * PAIRS + p;
        const float* xp = x2 + pair * 960;

        // ---- Phase A: x frag from global, 1 mfma, LReLU, y -> LDS (bf16) ----
        {
            short8 af;
            int s = si * 16 + l15;
            #pragma unroll
            for (int i = 0; i < 8; ++i) {
                int k = lq * 8 + i;
                af[i] = f2bf((k < 30) ? xp[s * 30 + k] : 0.0f);
            }
            f32x4 c = {0.0f, 0.0f, 0.0f, 0.0f};
            c = __builtin_amdgcn_mfma_f32_16x16x32_bf16(af, blw, c, 0, 0, 0);
            #pragma unroll
            for (int r = 0; r < 4; ++r) {
                float yv = c[r] + lbv;
                yv = LRELU(yv);
                y_lds[si * 16 + lq * 4 + r][di * 16 + l15] = f2bf(yv);
            }
        }
        __syncthreads();

        // ---- Phase B: 3 mfma per wave -> qkv; scatter to q16p/kT16/vT ----
        {
            short8 a0 = *(const short8*)&y_lds[l15][lq * 8];
            short8 a1 = *(const short8*)&y_lds[16 + l15][lq * 8];
            #pragma unroll
            for (int t = 0; t < 3; ++t) {
                int T   = 3 * w + t;
                int jt  = T >> 1;
                int si_ = T & 1;
                short8 a = si_ ? a1 : a0;
                short8 b = (jt == jtA) ? biwA : biwB;
                float ibv = (jt == jtA) ? ibvA : ibvB;
                f32x4 c = {0.0f, 0.0f, 0.0f, 0.0f};
                c = __builtin_amdgcn_mfma_f32_16x16x32_bf16(a, b, c, 0, 0, 0);
                int j  = jt * 16 + l15;
                int s0 = si_ * 16 + lq * 4;
                if (j < 30) {
                    int h = j / 5, e = j - 5 * h;
                    #pragma unroll
                    for (int r = 0; r < 4; ++r)
                        q16p[s0 + r][h * 8 + e] = (half_t)(c[r] + ibv);
                } else if (j < 60) {
                    int jj = j - 30; int h = jj / 5, e = jj - 5 * h;
                    #pragma unroll
                    for (int r = 0; r < 4; ++r)
                        kT16[h][e][s0 + r] = (half_t)(c[r] + ibv);
                } else if (j < 90) {
                    int jj = j - 60; int h = jj / 5, e = jj - 5 * h;
                    #pragma unroll
                    for (int r = 0; r < 4; ++r)
                        vT[h][e][s0 + r] = c[r] + ibv;
                }
            }
        }
        __syncthreads();

        // ---- Phase C: scores row (h,s) -> softmax -> att (192 threads) ----
        if (tid < 192) {
            const int h = tid >> 5, s = tid & 31;
            const float rs5 = 0.44721359549995793f;  // 1/sqrt(5)
            half8 qv = *(const half8*)&q16p[s][h * 8];
            float qf[5];
            #pragma unroll
            for (int e = 0; e < 5; ++e) qf[e] = (float)qv[e];
            float sc[32];
            #pragma unroll
            for (int t = 0; t < 32; ++t) sc[t] = 0.0f;
            #pragma unroll
            for (int e = 0; e < 5; ++e) {
                const half_t* kr = &kT16[h][e][0];
                half8 k0 = *(const half8*)(kr);
                half8 k1 = *(const half8*)(kr + 8);
                half8 k2 = *(const half8*)(kr + 16);
                half8 k3 = *(const half8*)(kr + 24);
                float qe = qf[e];
                #pragma unroll
                for (int i = 0; i < 8; ++i) {
                    sc[i]      = fmaf(qe, (float)k0[i], sc[i]);
                    sc[8 + i]  = fmaf(qe, (float)k1[i], sc[8 + i]);
                    sc[16 + i] = fmaf(qe, (float)k2[i], sc[16 + i]);
                    sc[24 + i] = fmaf(qe, (float)k3[i], sc[24 + i]);
                }
            }
            float m = sc[0] * rs5;
            #pragma unroll
            for (int t = 0; t < 32; ++t) { sc[t] *= rs5; m = fmaxf(m, sc[t]); }
            float Z = 0.0f;
            #pragma unroll
            for (int t = 0; t < 32; ++t) { sc[t] = __expf(sc[t] - m); Z += sc[t]; }
            float rZ = (1.0f / 32.0f) / Z;
            #pragma unroll
            for (int t = 0; t < 32; ++t) att[tid][t] = sc[t] * rZ;
        }
        __syncthreads();

        // ---- Phase D: abar[h][t] = sum_s att (mean folded into att) ----
        if (tid < 192) {
            const int h = tid >> 5, t = tid & 31;
            float sum = 0.0f;
            #pragma unroll
            for (int s = 0; s < 32; ++s) sum += att[h * 32 + s][t];
            abar[h][t] = sum;
        }
        __syncthreads();

        // ---- Phase E: obar[he] = sum_t abar[h][t]*vT[h][e][t], 240 thr ----
        if (tid < 240) {
            const int he = tid >> 3, tq = tid & 7;
            const int h = he / 5, e = he - 5 * h;
            f32x4 av = *(const f32x4*)&abar[h][tq * 4];
            f32x4 vv = *(const f32x4*)&vT[h][e][tq * 4];
            float part = av.x * vv.x + av.y * vv.y + av.z * vv.z + av.w * vv.w;
            part += __shfl_down(part, 4, 8);
            part += __shfl_down(part, 2, 8);
            part += __shfl_down(part, 1, 8);
            if (tq == 0) obar[he] = part;
        }
        __syncthreads();

        // ---- Phase F: h1 = obar @ ow^T + ob (ow from global/L1), 240 thr ----
        if (tid < 240) {
            const int d = tid >> 3, jq = tid & 7;
            f32x4 ov = *(const f32x4*)&obar[jq * 4];
            float part = 0.0f;
            #pragma unroll
            for (int i = 0; i < 4; ++i) {
                int j = jq * 4 + i;
                if (j < 30) part = fmaf(ov[i], ow[d * 30 + j], part);
            }
            part += __shfl_down(part, 4, 8);
            part += __shfl_down(part, 2, 8);
            part += __shfl_down(part, 1, 8);
            if (jq == 0) h1out[pair * 30 + d] = part + ob[d];
        }
        // no barrier needed here: next Phase A only writes y_lds (last read
        // before bar after Phase B of this pair); next writes to q16p/kT/vT
        // happen after the next pair's first barrier.
    }
}

// ---------------------------------------------------------------------------
// Kernel 2: first-hop graph layer (S=17) + MLP + softmax. Unchanged (passing).
// ---------------------------------------------------------------------------
__global__ __launch_bounds__(256, 2) void gl1_mlp_kernel(
    const float* __restrict__ h1, const float* __restrict__ self_feat,
    const float* __restrict__ lw, const float* __restrict__ lb,
    const float* __restrict__ iw, const float* __restrict__ ib,
    const float* __restrict__ ow, const float* __restrict__ ob,
    const float* __restrict__ cw1, const float* __restrict__ cb1,
    const float* __restrict__ cw2, const float* __restrict__ cb2,
    const float* __restrict__ cw3, const float* __restrict__ cb3,
    float* __restrict__ out)
{
    __shared__ float w_lw[32][31];
    __shared__ float w_lb[32];
    __shared__ float w_iw[96][31];
    __shared__ float w_ib[96];
    __shared__ float w_ow[30][31];
    __shared__ float w_ob[32];
    __shared__ float xb[17][33];
    __shared__ float qkvb[17][97];
    __shared__ float att[102][19];
    __shared__ float abar[6][19];
    __shared__ float obar[32];
    __shared__ float emb[32];
    __shared__ float hb1[64];
    __shared__ float hb2[64];
    __shared__ float lg[2];

    const int tid = threadIdx.x;
    const int b = blockIdx.x;

    for (int i = tid; i < 32 * 31; i += 256) (&w_lw[0][0])[i] = 0.0f;
    for (int i = tid; i < 96 * 31; i += 256) (&w_iw[0][0])[i] = 0.0f;
    if (tid < 32) w_lb[tid] = 0.0f;
    if (tid < 96) w_ib[tid] = 0.0f;
    __syncthreads();
    for (int i = tid; i < 900;  i += 256) w_lw[i / 30][i % 30] = lw[i];
    for (int i = tid; i < 2700; i += 256) w_iw[i / 30][i % 30] = iw[i];
    for (int i = tid; i < 900;  i += 256) w_ow[i / 30][i % 30] = ow[i];
    if (tid < 30) { w_lb[tid] = lb[tid]; w_ob[tid] = ob[tid]; }
    if (tid < 90) w_ib[tid] = ib[tid];
    for (int i = tid; i < 480; i += 256)
        xb[i / 30][i % 30] = h1[(size_t)b * 480 + i];
    if (tid < 30) xb[16][tid] = self_feat[(size_t)b * 30 + tid];
    __syncthreads();

    {
        auto compY = [&](int idx) -> float {
            int s = idx >> 5, d = idx & 31;
            float a = w_lb[d];
            #pragma unroll
            for (int k = 0; k < 30; ++k) a = fmaf(xb[s][k], w_lw[d][k], a);
            return LRELU(a);
        };
        float y0 = compY(tid);
        float y1 = (tid + 256 < 544) ? compY(tid + 256) : 0.0f;
        bool has2 = (tid + 512 < 544);
        float y2 = has2 ? compY(tid + 512) : 0.0f;
        __syncthreads();
        { int s = tid >> 5, d = tid & 31; xb[s][d] = y0; }
        if (tid + 256 < 544) { int idx = tid + 256; xb[idx >> 5][idx & 31] = y1; }
        if (has2) { int idx = tid + 512; xb[idx >> 5][idx & 31] = y2; }
    }
    __syncthreads();

    for (int idx = tid; idx < 17 * 96; idx += 256) {
        int s = idx / 96, j = idx % 96;
        float a = w_ib[j];
        #pragma unroll
        for (int d = 0; d < 30; ++d) a = fmaf(xb[s][d], w_iw[j][d], a);
        qkvb[s][j] = a;
    }
    __syncthreads();

    if (tid < 102) {
        const int h = tid / 17, s = tid % 17;
        const float rs5 = 0.44721359549995793f;
        const int cq = h * 5, ck = 30 + h * 5;
        float q0 = qkvb[s][cq], q1 = qkvb[s][cq + 1], q2 = qkvb[s][cq + 2];
        float q3 = qkvb[s][cq + 3], q4 = qkvb[s][cq + 4];
        float sc[17];
        #pragma unroll
        for (int t = 0; t < 17; ++t) {
            float d0 = q0 * qkvb[t][ck] + q1 * qkvb[t][ck + 1];
            float d1 = q2 * qkvb[t][ck + 2] + q3 * qkvb[t][ck + 3];
            sc[t] = (d0 + d1 + q4 * qkvb[t][ck + 4]) * rs5;
        }
        float m = sc[0];
        #pragma unroll
        for (int t = 1; t < 17; ++t) m = fmaxf(m, sc[t]);
        float Z = 0.0f;
        #pragma unroll
        for (int t = 0; t < 17; ++t) { sc[t] = __expf(sc[t] - m); Z += sc[t]; }
        float rZ = 1.0f / Z;
        #pragma unroll
        for (int t = 0; t < 17; ++t) att[tid][t] = sc[t] * rZ;
    }
    __syncthreads();

    if (tid < 102) {
        const int h = tid / 17, t = tid % 17;
        float sum = 0.0f;
        #pragma unroll
        for (int s = 0; s < 17; ++s) sum += att[h * 17 + s][t];
        abar[h][t] = sum * (1.0f / 17.0f);
    }
    __syncthreads();

    if (tid < 30) {
        const int h = tid / 5, e = tid % 5;
        const int cv = 60 + h * 5 + e;
        float acc = 0.0f;
        #pragma unroll
        for (int t = 0; t < 17; ++t) acc = fmaf(abar[h][t], qkvb[t][cv], acc);
        obar[tid] = acc;
    }
    __syncthreads();

    if (tid < 30) {
        float r = w_ob[tid];
        #pragma unroll
        for (int j = 0; j < 30; ++j) r = fmaf(obar[j], w_ow[tid][j], r);
        emb[tid] = r;
    }
    __syncthreads();

    if (tid < 64) {
        float a = cb1[tid];
        #pragma unroll
        for (int k = 0; k < 30; ++k) a = fmaf(emb[k], cw1[tid * 30 + k], a);
        hb1[tid] = LRELU(a);
    }
    __syncthreads();
    if (tid < 64) {
        float a = cb2[tid];
        #pragma unroll
        for (int k = 0; k < 64; ++k) a = fmaf(hb1[k], cw2[tid * 64 + k], a);
        hb2[tid] = LRELU(a);
    }
    __syncthreads();
    if (tid < 2) {
        float a = cb3[tid];
        #pragma unroll
        for (int k = 0; k < 64; ++k) a = fmaf(hb2[k], cw3[tid * 64 + k], a);
        lg[tid] = a;
    }
    __syncthreads();
    if (tid < 2) {
        float m = fmaxf(lg[0], lg[1]);
        float e0 = __expf(lg[0] - m), e1 = __expf(lg[1] - m);
        float p = ((tid == 0) ? e0 : e1) / (e0 + e1);
        out[(size_t)b * 2 + tid] = p;
    }
}

extern "C" void kernel_launch(void* const* d_in, const int* in_sizes, int n_in,
                              void* d_out, int out_size, void* d_ws, size_t ws_size,
                              hipStream_t stream)
{
    const float* x2        = (const float*)d_in[0];
    const float* self_feat = (const float*)d_in[1];
    const float* lin_w2 = (const float*)d_in[2];
    const float* lin_b2 = (const float*)d_in[3];
    const float* in_w2  = (const float*)d_in[4];
    const float* in_b2  = (const float*)d_in[5];
    const float* out_w2 = (const float*)d_in[6];
    const float* out_b2 = (const float*)d_in[7];
    const float* lin_w1 = (const float*)d_in[8];
    const float* lin_b1 = (const float*)d_in[9];
    const float* in_w1  = (const float*)d_in[10];
    const float* in_b1  = (const float*)d_in[11];
    const float* out_w1 = (const float*)d_in[12];
    const float* out_b1 = (const float*)d_in[13];
    const float* cw1 = (const float*)d_in[14];
    const float* cb1 = (const float*)d_in[15];
    const float* cw2 = (const float*)d_in[16];
    const float* cb2 = (const float*)d_in[17];
    const float* cw3 = (const float*)d_in[18];
    const float* cb3 = (const float*)d_in[19];
    float* outp = (float*)d_out;

    float* h1 = (float*)d_ws;   // 65536 * 30 floats = 7.86 MB

    gl2_kernel<<<(4096 * 16) / PAIRS, 256, 0, stream>>>(
        x2, lin_w2, lin_b2, in_w2, in_b2, out_w2, out_b2, h1);

    gl1_mlp_kernel<<<4096, 256, 0, stream>>>(
        h1, self_feat, lin_w1, lin_b1, in_w1, in_b1, out_w1, out_b1,
        cw1, cb1, cw2, cb2, cw3, cb3, outp);
}

// Round 3
// 635.723 us; speedup vs baseline: 2.6408x; 1.0391x over previous
//
#include <hip/hip_runtime.h>
#include <math.h>

#define LRELU(v) ((v) > 0.0f ? (v) : 0.02f * (v))

typedef __attribute__((ext_vector_type(8))) short  short8;   // 8 bf16 in 4 VGPRs
typedef __attribute__((ext_vector_type(4))) float  f32x4;
typedef _Float16 half_t;
typedef __attribute__((ext_vector_type(8))) _Float16 half8;

__device__ inline short f2bf(float f) {
    unsigned u = __builtin_bit_cast(unsigned, f);
    unsigned r = (u + 0x7FFFu + ((u >> 16) & 1u)) >> 16;   // RNE
    return (short)r;
}

#define PAIRS 8
#define NP1   2

// ---------------------------------------------------------------------------
// Kernel 1: second-hop graph layer, MFMA edition (unchanged from R2, verified).
// ---------------------------------------------------------------------------
__global__ __launch_bounds__(256, 4) void gl2_kernel(
    const float* __restrict__ x2,
    const float* __restrict__ lw, const float* __restrict__ lb,
    const float* __restrict__ iw, const float* __restrict__ ib,
    const float* __restrict__ ow, const float* __restrict__ ob,
    float* __restrict__ h1out)
{
    __shared__ short  y_lds[32][40];
    __shared__ half_t q16p[32][48];
    __shared__ half_t kT16[6][5][32];
    __shared__ float  vT[6][5][36];
    __shared__ float  att[192][33];
    __shared__ float  abar[6][32];
    __shared__ float  obar[32];

    const int tid  = threadIdx.x;
    const int lane = tid & 63;
    const int w    = tid >> 6;
    const int l15  = lane & 15;
    const int lq   = lane >> 4;

    for (int i = tid; i < (32 * 48) / 2; i += 256) ((int*)q16p)[i] = 0;
    if (tid < 2) obar[30 + tid] = 0.0f;

    const int di = w & 1, si = w >> 1;
    short8 blw;
    float  lbv;
    {
        int d = di * 16 + l15;
        #pragma unroll
        for (int i = 0; i < 8; ++i) {
            int k = lq * 8 + i;
            float v = (d < 30 && k < 30) ? lw[d * 30 + k] : 0.0f;
            blw[i] = f2bf(v);
        }
        lbv = (d < 30) ? lb[d] : 0.0f;
    }
    const int jtA = (3 * w) >> 1;
    const int jtB = (3 * w + 2) >> 1;
    short8 biwA, biwB;
    float  ibvA, ibvB;
    {
        int jA = jtA * 16 + l15, jB = jtB * 16 + l15;
        #pragma unroll
        for (int i = 0; i < 8; ++i) {
            int k = lq * 8 + i;
            biwA[i] = f2bf((jA < 90 && k < 30) ? iw[jA * 30 + k] : 0.0f);
            biwB[i] = f2bf((jB < 90 && k < 30) ? iw[jB * 30 + k] : 0.0f);
        }
        ibvA = (jA < 90) ? ib[jA] : 0.0f;
        ibvB = (jB < 90) ? ib[jB] : 0.0f;
    }
    __syncthreads();

    for (int p = 0; p < PAIRS; ++p) {
        const long pair = (long)blockIdx.x * PAIRS + p;
        const float* xp = x2 + pair * 960;

        {
            short8 af;
            int s = si * 16 + l15;
            #pragma unroll
            for (int i = 0; i < 8; ++i) {
                int k = lq * 8 + i;
                af[i] = f2bf((k < 30) ? xp[s * 30 + k] : 0.0f);
            }
            f32x4 c = {0.0f, 0.0f, 0.0f, 0.0f};
            c = __builtin_amdgcn_mfma_f32_16x16x32_bf16(af, blw, c, 0, 0, 0);
            #pragma unroll
            for (int r = 0; r < 4; ++r) {
                float yv = c[r] + lbv;
                yv = LRELU(yv);
                y_lds[si * 16 + lq * 4 + r][di * 16 + l15] = f2bf(yv);
            }
        }
        __syncthreads();

        {
            short8 a0 = *(const short8*)&y_lds[l15][lq * 8];
            short8 a1 = *(const short8*)&y_lds[16 + l15][lq * 8];
            #pragma unroll
            for (int t = 0; t < 3; ++t) {
                int T   = 3 * w + t;
                int jt  = T >> 1;
                int si_ = T & 1;
                short8 a = si_ ? a1 : a0;
                short8 b = (jt == jtA) ? biwA : biwB;
                float ibv = (jt == jtA) ? ibvA : ibvB;
                f32x4 c = {0.0f, 0.0f, 0.0f, 0.0f};
                c = __builtin_amdgcn_mfma_f32_16x16x32_bf16(a, b, c, 0, 0, 0);
                int j  = jt * 16 + l15;
                int s0 = si_ * 16 + lq * 4;
                if (j < 30) {
                    int h = j / 5, e = j - 5 * h;
                    #pragma unroll
                    for (int r = 0; r < 4; ++r)
                        q16p[s0 + r][h * 8 + e] = (half_t)(c[r] + ibv);
                } else if (j < 60) {
                    int jj = j - 30; int h = jj / 5, e = jj - 5 * h;
                    #pragma unroll
                    for (int r = 0; r < 4; ++r)
                        kT16[h][e][s0 + r] = (half_t)(c[r] + ibv);
                } else if (j < 90) {
                    int jj = j - 60; int h = jj / 5, e = jj - 5 * h;
                    #pragma unroll
                    for (int r = 0; r < 4; ++r)
                        vT[h][e][s0 + r] = c[r] + ibv;
                }
            }
        }
        __syncthreads();

        if (tid < 192) {
            const int h = tid >> 5, s = tid & 31;
            const float rs5 = 0.44721359549995793f;
            half8 qv = *(const half8*)&q16p[s][h * 8];
            float qf[5];
            #pragma unroll
            for (int e = 0; e < 5; ++e) qf[e] = (float)qv[e];
            float sc[32];
            #pragma unroll
            for (int t = 0; t < 32; ++t) sc[t] = 0.0f;
            #pragma unroll
            for (int e = 0; e < 5; ++e) {
                const half_t* kr = &kT16[h][e][0];
                half8 k0 = *(const half8*)(kr);
                half8 k1 = *(const half8*)(kr + 8);
                half8 k2 = *(const half8*)(kr + 16);
                half8 k3 = *(const half8*)(kr + 24);
                float qe = qf[e];
                #pragma unroll
                for (int i = 0; i < 8; ++i) {
                    sc[i]      = fmaf(qe, (float)k0[i], sc[i]);
                    sc[8 + i]  = fmaf(qe, (float)k1[i], sc[8 + i]);
                    sc[16 + i] = fmaf(qe, (float)k2[i], sc[16 + i]);
                    sc[24 + i] = fmaf(qe, (float)k3[i], sc[24 + i]);
                }
            }
            float m = sc[0] * rs5;
            #pragma unroll
            for (int t = 0; t < 32; ++t) { sc[t] *= rs5; m = fmaxf(m, sc[t]); }
            float Z = 0.0f;
            #pragma unroll
            for (int t = 0; t < 32; ++t) { sc[t] = __expf(sc[t] - m); Z += sc[t]; }
            float rZ = (1.0f / 32.0f) / Z;
            #pragma unroll
            for (int t = 0; t < 32; ++t) att[tid][t] = sc[t] * rZ;
        }
        __syncthreads();

        if (tid < 192) {
            const int h = tid >> 5, t = tid & 31;
            float sum = 0.0f;
            #pragma unroll
            for (int s = 0; s < 32; ++s) sum += att[h * 32 + s][t];
            abar[h][t] = sum;
        }
        __syncthreads();

        if (tid < 240) {
            const int he = tid >> 3, tq = tid & 7;
            const int h = he / 5, e = he - 5 * h;
            f32x4 av = *(const f32x4*)&abar[h][tq * 4];
            f32x4 vv = *(const f32x4*)&vT[h][e][tq * 4];
            float part = av.x * vv.x + av.y * vv.y + av.z * vv.z + av.w * vv.w;
            part += __shfl_down(part, 4, 8);
            part += __shfl_down(part, 2, 8);
            part += __shfl_down(part, 1, 8);
            if (tq == 0) obar[he] = part;
        }
        __syncthreads();

        if (tid < 240) {
            const int d = tid >> 3, jq = tid & 7;
            f32x4 ov = *(const f32x4*)&obar[jq * 4];
            float part = 0.0f;
            #pragma unroll
            for (int i = 0; i < 4; ++i) {
                int j = jq * 4 + i;
                if (j < 30) part = fmaf(ov[i], ow[d * 30 + j], part);
            }
            part += __shfl_down(part, 4, 8);
            part += __shfl_down(part, 2, 8);
            part += __shfl_down(part, 1, 8);
            if (jq == 0) h1out[pair * 30 + d] = part + ob[d];
        }
    }
}

// ---------------------------------------------------------------------------
// Kernel 2: first-hop graph layer, MFMA edition, S=17 padded to 32, fused MLP.
// NP1 nodes per block. Same phase structure as gl2; masked softmax (t>=17),
// Phase-D sum over s<17, mean 1/17; emb -> in-block MLP 30->64->64->2 + softmax.
// ---------------------------------------------------------------------------
__global__ __launch_bounds__(256, 4) void gl1_mlp_kernel(
    const float* __restrict__ h1, const float* __restrict__ self_feat,
    const float* __restrict__ lw, const float* __restrict__ lb,
    const float* __restrict__ iw, const float* __restrict__ ib,
    const float* __restrict__ ow, const float* __restrict__ ob,
    const float* __restrict__ cw1, const float* __restrict__ cb1,
    const float* __restrict__ cw2, const float* __restrict__ cb2,
    const float* __restrict__ cw3, const float* __restrict__ cb3,
    float* __restrict__ out)
{
    __shared__ short  y_lds[32][40];
    __shared__ half_t q16p[32][48];
    __shared__ half_t kT16[6][5][32];
    __shared__ float  vT[6][5][36];
    __shared__ float  att[192][33];
    __shared__ float  abar[6][32];
    __shared__ float  obar[32];
    __shared__ float  embb[32];
    __shared__ float  hb1[64];
    __shared__ float  hb2[64];
    __shared__ float  lg[2];

    const int tid  = threadIdx.x;
    const int lane = tid & 63;
    const int w    = tid >> 6;
    const int l15  = lane & 15;
    const int lq   = lane >> 4;

    for (int i = tid; i < (32 * 48) / 2; i += 256) ((int*)q16p)[i] = 0;
    if (tid < 2) obar[30 + tid] = 0.0f;

    const int di = w & 1, si = w >> 1;
    short8 blw;
    float  lbv;
    {
        int d = di * 16 + l15;
        #pragma unroll
        for (int i = 0; i < 8; ++i) {
            int k = lq * 8 + i;
            float v = (d < 30 && k < 30) ? lw[d * 30 + k] : 0.0f;
            blw[i] = f2bf(v);
        }
        lbv = (d < 30) ? lb[d] : 0.0f;
    }
    const int jtA = (3 * w) >> 1;
    const int jtB = (3 * w + 2) >> 1;
    short8 biwA, biwB;
    float  ibvA, ibvB;
    {
        int jA = jtA * 16 + l15, jB = jtB * 16 + l15;
        #pragma unroll
        for (int i = 0; i < 8; ++i) {
            int k = lq * 8 + i;
            biwA[i] = f2bf((jA < 90 && k < 30) ? iw[jA * 30 + k] : 0.0f);
            biwB[i] = f2bf((jB < 90 && k < 30) ? iw[jB * 30 + k] : 0.0f);
        }
        ibvA = (jA < 90) ? ib[jA] : 0.0f;
        ibvB = (jB < 90) ? ib[jB] : 0.0f;
    }
    __syncthreads();

    for (int p = 0; p < NP1; ++p) {
        const long node = (long)blockIdx.x * NP1 + p;
        const float* h1p = h1 + node * 480;        // 16 rows x 30
        const float* sfp = self_feat + node * 30;  // row 16

        // ---- Phase A: rows 0..15 = h1, row 16 = self_feat, rows 17..31 = 0 ----
        {
            short8 af;
            if (si == 0) {
                int s = l15;
                #pragma unroll
                for (int i = 0; i < 8; ++i) {
                    int k = lq * 8 + i;
                    af[i] = f2bf((k < 30) ? h1p[s * 30 + k] : 0.0f);
                }
            } else {
                #pragma unroll
                for (int i = 0; i < 8; ++i) {
                    int k = lq * 8 + i;
                    af[i] = (l15 == 0 && k < 30) ? f2bf(sfp[k]) : (short)0;
                }
            }
            f32x4 c = {0.0f, 0.0f, 0.0f, 0.0f};
            c = __builtin_amdgcn_mfma_f32_16x16x32_bf16(af, blw, c, 0, 0, 0);
            #pragma unroll
            for (int r = 0; r < 4; ++r) {
                float yv = c[r] + lbv;
                yv = LRELU(yv);
                // rows s>=17 hold LReLU(lb): harmless, masked downstream
                y_lds[si * 16 + lq * 4 + r][di * 16 + l15] = f2bf(yv);
            }
        }
        __syncthreads();

        // ---- Phase B: qkv ----
        {
            short8 a0 = *(const short8*)&y_lds[l15][lq * 8];
            short8 a1 = *(const short8*)&y_lds[16 + l15][lq * 8];
            #pragma unroll
            for (int t = 0; t < 3; ++t) {
                int T   = 3 * w + t;
                int jt  = T >> 1;
                int si_ = T & 1;
                short8 a = si_ ? a1 : a0;
                short8 b = (jt == jtA) ? biwA : biwB;
                float ibv = (jt == jtA) ? ibvA : ibvB;
                f32x4 c = {0.0f, 0.0f, 0.0f, 0.0f};
                c = __builtin_amdgcn_mfma_f32_16x16x32_bf16(a, b, c, 0, 0, 0);
                int j  = jt * 16 + l15;
                int s0 = si_ * 16 + lq * 4;
                if (j < 30) {
                    int h = j / 5, e = j - 5 * h;
                    #pragma unroll
                    for (int r = 0; r < 4; ++r)
                        q16p[s0 + r][h * 8 + e] = (half_t)(c[r] + ibv);
                } else if (j < 60) {
                    int jj = j - 30; int h = jj / 5, e = jj - 5 * h;
                    #pragma unroll
                    for (int r = 0; r < 4; ++r)
                        kT16[h][e][s0 + r] = (half_t)(c[r] + ibv);
                } else if (j < 90) {
                    int jj = j - 60; int h = jj / 5, e = jj - 5 * h;
                    #pragma unroll
                    for (int r = 0; r < 4; ++r)
                        vT[h][e][s0 + r] = c[r] + ibv;
                }
            }
        }
        __syncthreads();

        // ---- Phase C: scores + masked softmax (valid t < 17) ----
        if (tid < 192) {
            const int h = tid >> 5, s = tid & 31;
            const float rs5 = 0.44721359549995793f;
            half8 qv = *(const half8*)&q16p[s][h * 8];
            float qf[5];
            #pragma unroll
            for (int e = 0; e < 5; ++e) qf[e] = (float)qv[e];
            float sc[32];
            #pragma unroll
            for (int t = 0; t < 32; ++t) sc[t] = 0.0f;
            #pragma unroll
            for (int e = 0; e < 5; ++e) {
                const half_t* kr = &kT16[h][e][0];
                half8 k0 = *(const half8*)(kr);
                half8 k1 = *(const half8*)(kr + 8);
                half8 k2 = *(const half8*)(kr + 16);
                half8 k3 = *(const half8*)(kr + 24);
                float qe = qf[e];
                #pragma unroll
                for (int i = 0; i < 8; ++i) {
                    sc[i]      = fmaf(qe, (float)k0[i], sc[i]);
                    sc[8 + i]  = fmaf(qe, (float)k1[i], sc[8 + i]);
                    sc[16 + i] = fmaf(qe, (float)k2[i], sc[16 + i]);
                    sc[24 + i] = fmaf(qe, (float)k3[i], sc[24 + i]);
                }
            }
            #pragma unroll
            for (int t = 17; t < 32; ++t) sc[t] = -1e30f;   // mask padding
            float m = sc[0] * rs5;
            #pragma unroll
            for (int t = 0; t < 17; ++t) { sc[t] *= rs5; m = fmaxf(m, sc[t]); }
            float Z = 0.0f;
            #pragma unroll
            for (int t = 0; t < 32; ++t) { sc[t] = __expf(sc[t] - m); Z += sc[t]; }
            float rZ = (1.0f / 17.0f) / Z;
            #pragma unroll
            for (int t = 0; t < 32; ++t) att[tid][t] = sc[t] * rZ;
        }
        __syncthreads();

        // ---- Phase D: abar over valid s < 17 ----
        if (tid < 192) {
            const int h = tid >> 5, t = tid & 31;
            float sum = 0.0f;
            #pragma unroll
            for (int s = 0; s < 17; ++s) sum += att[h * 32 + s][t];
            abar[h][t] = sum;   // zero for t>=17 (masked att)
        }
        __syncthreads();

        // ---- Phase E: obar ----
        if (tid < 240) {
            const int he = tid >> 3, tq = tid & 7;
            const int h = he / 5, e = he - 5 * h;
            f32x4 av = *(const f32x4*)&abar[h][tq * 4];
            f32x4 vv = *(const f32x4*)&vT[h][e][tq * 4];
            float part = av.x * vv.x + av.y * vv.y + av.z * vv.z + av.w * vv.w;
            part += __shfl_down(part, 4, 8);
            part += __shfl_down(part, 2, 8);
            part += __shfl_down(part, 1, 8);
            if (tq == 0) obar[he] = part;
        }
        __syncthreads();

        // ---- Phase F: emb = obar @ ow^T + ob -> LDS ----
        if (tid < 240) {
            const int d = tid >> 3, jq = tid & 7;
            f32x4 ov = *(const f32x4*)&obar[jq * 4];
            float part = 0.0f;
            #pragma unroll
            for (int i = 0; i < 4; ++i) {
                int j = jq * 4 + i;
                if (j < 30) part = fmaf(ov[i], ow[d * 30 + j], part);
            }
            part += __shfl_down(part, 4, 8);
            part += __shfl_down(part, 2, 8);
            part += __shfl_down(part, 1, 8);
            if (jq == 0) embb[d] = part + ob[d];
        }
        __syncthreads();

        // ---- MLP layer 1: 30 -> 64, 4 threads per output ----
        {
            const int o = tid >> 2, kq = tid & 3;
            float part = 0.0f;
            #pragma unroll
            for (int i = 0; i < 8; ++i) {
                int k = kq * 8 + i;
                if (k < 30) part = fmaf(embb[k], cw1[o * 30 + k], part);
            }
            part += __shfl_down(part, 2, 4);
            part += __shfl_down(part, 1, 4);
            if (kq == 0) hb1[o] = LRELU(part + cb1[o]);
        }
        __syncthreads();

        // ---- MLP layer 2: 64 -> 64 ----
        {
            const int o = tid >> 2, kq = tid & 3;
            float part = 0.0f;
            #pragma unroll
            for (int i = 0; i < 16; ++i) {
                int k = kq * 16 + i;
                part = fmaf(hb1[k], cw2[o * 64 + k], part);
            }
            part += __shfl_down(part, 2, 4);
            part += __shfl_down(part, 1, 4);
            if (kq == 0) hb2[o] = LRELU(part + cb2[o]);
        }
        __syncthreads();

        // ---- MLP layer 3: 64 -> 2 (wave 0 -> class 0, wave 1 -> class 1) ----
        if (tid < 128) {
            const int c = tid >> 6, k = tid & 63;
            float part = hb2[k] * cw3[c * 64 + k];
            part += __shfl_down(part, 32);
            part += __shfl_down(part, 16);
            part += __shfl_down(part, 8);
            part += __shfl_down(part, 4);
            part += __shfl_down(part, 2);
            part += __shfl_down(part, 1);
            if (k == 0) lg[c] = part + cb3[c];
        }
        __syncthreads();

        if (tid < 2) {
            float m = fmaxf(lg[0], lg[1]);
            float e0 = __expf(lg[0] - m), e1 = __expf(lg[1] - m);
            float pr = ((tid == 0) ? e0 : e1) / (e0 + e1);
            out[node * 2 + tid] = pr;
        }
        __syncthreads();   // protect lg/hb against next pair's overwrites
    }
}

extern "C" void kernel_launch(void* const* d_in, const int* in_sizes, int n_in,
                              void* d_out, int out_size, void* d_ws, size_t ws_size,
                              hipStream_t stream)
{
    const float* x2        = (const float*)d_in[0];
    const float* self_feat = (const float*)d_in[1];
    const float* lin_w2 = (const float*)d_in[2];
    const float* lin_b2 = (const float*)d_in[3];
    const float* in_w2  = (const float*)d_in[4];
    const float* in_b2  = (const float*)d_in[5];
    const float* out_w2 = (const float*)d_in[6];
    const float* out_b2 = (const float*)d_in[7];
    const float* lin_w1 = (const float*)d_in[8];
    const float* lin_b1 = (const float*)d_in[9];
    const float* in_w1  = (const float*)d_in[10];
    const float* in_b1  = (const float*)d_in[11];
    const float* out_w1 = (const float*)d_in[12];
    const float* out_b1 = (const float*)d_in[13];
    const float* cw1 = (const float*)d_in[14];
    const float* cb1 = (const float*)d_in[15];
    const float* cw2 = (const float*)d_in[16];
    const float* cb2 = (const float*)d_in[17];
    const float* cw3 = (const float*)d_in[18];
    const float* cb3 = (const float*)d_in[19];
    float* outp = (float*)d_out;

    float* h1 = (float*)d_ws;   // 65536 * 30 floats = 7.86 MB

    gl2_kernel<<<(4096 * 16) / PAIRS, 256, 0, stream>>>(
        x2, lin_w2, lin_b2, in_w2, in_b2, out_w2, out_b2, h1);

    gl1_mlp_kernel<<<4096 / NP1, 256, 0, stream>>>(
        h1, self_feat, lin_w1, lin_b1, in_w1, in_b1, out_w1, out_b1,
        cw1, cb1, cw2, cb2, cw3, cb3, outp);
}

// Round 4
// 573.200 us; speedup vs baseline: 2.9289x; 1.1091x over previous
//
#include <hip/hip_runtime.h>
#include <math.h>

#define LRELU(v) ((v) > 0.0f ? (v) : 0.02f * (v))

typedef __attribute__((ext_vector_type(8)))  short short8;   // 8 bf16 / 4 VGPRs
typedef __attribute__((ext_vector_type(4)))  float f32x4;
typedef __attribute__((ext_vector_type(16))) float f32x16;
typedef __attribute__((ext_vector_type(2)))  int   int2v;

__device__ inline short f2bf(float f) {                       // RNE
    unsigned u = __builtin_bit_cast(unsigned, f);
    unsigned r = (u + 0x7FFFu + ((u >> 16) & 1u)) >> 16;
    return (short)r;
}
__device__ inline int pack_bf16_trunc(float a, float b) {     // a->lo, b->hi
    unsigned ua = __builtin_bit_cast(unsigned, a);
    unsigned ub = __builtin_bit_cast(unsigned, b);
    return (int)((ub & 0xFFFF0000u) | (ua >> 16));
}
__device__ inline float bf16s_to_f(unsigned short u) {
    unsigned v = ((unsigned)u) << 16;
    return __builtin_bit_cast(float, v);
}

#define PAIRS 8
#define NP1   2
#define RS5   0.44721359549995793f   // 1/sqrt(5)

// ---------------------------------------------------------------------------
// Kernel 1: second-hop graph layer. MFMA for P1/P2 (16x16x32) AND for the
// 32x32 per-head score matrices (32x32x16), softmax in C-layout registers.
// ---------------------------------------------------------------------------
__global__ __launch_bounds__(256, 4) void gl2_kernel(
    const float* __restrict__ x2,
    const float* __restrict__ lw, const float* __restrict__ lb,
    const float* __restrict__ iw, const float* __restrict__ ib,
    const float* __restrict__ ow, const float* __restrict__ ob,
    float* __restrict__ h1out)
{
    __shared__ short y_lds[32][40];     // y bf16, rows 80 B
    __shared__ short qmf[6][33][8];     // q bf16 [h][s][e], e>=5 zero, row 32 zero
    __shared__ short kmf[6][33][8];     // k bf16 [h][t][e], prescaled by 1/sqrt5
    __shared__ float vT[6][5][36];      // v fp32 [h][e][t]
    __shared__ short att2[6][32][40];   // att bf16 [h][s][t] (t stride 40)
    __shared__ float abar[6][32];
    __shared__ float obar[32];

    const int tid  = threadIdx.x;
    const int lane = tid & 63;
    const int w    = tid >> 6;
    const int l15  = lane & 15;
    const int lq   = lane >> 4;
    const int h5   = lane >> 5;
    const int scol = lane & 31;
    const int rowz = (lane < 32) ? scol : 32;   // lanes>=32 read the zero row

    for (int i = tid; i < (6 * 33 * 8) / 2; i += 256) {
        ((int*)qmf)[i] = 0; ((int*)kmf)[i] = 0;
    }
    if (tid < 2) obar[30 + tid] = 0.0f;

    // ---- persistent weight fragments (once per block) ----
    const int di = w & 1, si = w >> 1;
    short8 blw; float lbv;
    {
        int d = di * 16 + l15;
        #pragma unroll
        for (int i = 0; i < 8; ++i) {
            int k = lq * 8 + i;
            blw[i] = f2bf((d < 30 && k < 30) ? lw[d * 30 + k] : 0.0f);
        }
        lbv = (d < 30) ? lb[d] : 0.0f;
    }
    const int jtA = (3 * w) >> 1, jtB = (3 * w + 2) >> 1;
    short8 biwA, biwB; float ibvA, ibvB;
    {
        int jA = jtA * 16 + l15, jB = jtB * 16 + l15;
        #pragma unroll
        for (int i = 0; i < 8; ++i) {
            int k = lq * 8 + i;
            biwA[i] = f2bf((jA < 90 && k < 30) ? iw[jA * 30 + k] : 0.0f);
            biwB[i] = f2bf((jB < 90 && k < 30) ? iw[jB * 30 + k] : 0.0f);
        }
        ibvA = (jA < 90) ? ib[jA] : 0.0f;
        ibvB = (jB < 90) ? ib[jB] : 0.0f;
    }
    __syncthreads();

    for (int p = 0; p < PAIRS; ++p) {
        const long pair = (long)blockIdx.x * PAIRS + p;
        const float* xp = x2 + pair * 960;

        // ---- Phase A: x -> y (1 mfma), y -> LDS bf16 ----
        {
            short8 af;
            int s = si * 16 + l15;
            #pragma unroll
            for (int i = 0; i < 8; ++i) {
                int k = lq * 8 + i;
                af[i] = f2bf((k < 30) ? xp[s * 30 + k] : 0.0f);
            }
            f32x4 c = {0.0f, 0.0f, 0.0f, 0.0f};
            c = __builtin_amdgcn_mfma_f32_16x16x32_bf16(af, blw, c, 0, 0, 0);
            #pragma unroll
            for (int r = 0; r < 4; ++r) {
                float yv = c[r] + lbv;
                yv = LRELU(yv);
                y_lds[si * 16 + lq * 4 + r][di * 16 + l15] = f2bf(yv);
            }
        }
        __syncthreads();

        // ---- Phase B: qkv (3 mfma/wave), scatter to qmf/kmf/vT ----
        {
            short8 a0 = *(const short8*)&y_lds[l15][lq * 8];
            short8 a1 = *(const short8*)&y_lds[16 + l15][lq * 8];
            #pragma unroll
            for (int t = 0; t < 3; ++t) {
                int T = 3 * w + t, jt = T >> 1, si_ = T & 1;
                short8 a = si_ ? a1 : a0;
                short8 b = (jt == jtA) ? biwA : biwB;
                float ibv = (jt == jtA) ? ibvA : ibvB;
                f32x4 c = {0.0f, 0.0f, 0.0f, 0.0f};
                c = __builtin_amdgcn_mfma_f32_16x16x32_bf16(a, b, c, 0, 0, 0);
                int j = jt * 16 + l15;
                int s0 = si_ * 16 + lq * 4;
                if (j < 30) {
                    int h = j / 5, e = j - 5 * h;
                    #pragma unroll
                    for (int r = 0; r < 4; ++r)
                        qmf[h][s0 + r][e] = f2bf(c[r] + ibv);
                } else if (j < 60) {
                    int jj = j - 30; int h = jj / 5, e = jj - 5 * h;
                    #pragma unroll
                    for (int r = 0; r < 4; ++r)
                        kmf[h][s0 + r][e] = f2bf((c[r] + ibv) * RS5);
                } else if (j < 90) {
                    int jj = j - 60; int h = jj / 5, e = jj - 5 * h;
                    #pragma unroll
                    for (int r = 0; r < 4; ++r)
                        vT[h][e][s0 + r] = c[r] + ibv;
                }
            }
        }
        __syncthreads();

        // ---- Phase C: per-head scores via MFMA + softmax in C-layout ----
        // C[t][s]: s = lane&31 (col), rows t = (r&3)+8*(r>>2)+4*(lane>>5).
        if (w < 3) {
            #pragma unroll
            for (int hh = 0; hh < 2; ++hh) {
                const int h = 2 * w + hh;
                short8 af = *(const short8*)&kmf[h][rowz][0];  // A = K (m=t,k=e)
                short8 bf = *(const short8*)&qmf[h][rowz][0];  // B = Q^T (k=e,n=s)
                f32x16 c;
                #pragma unroll
                for (int r = 0; r < 16; ++r) c[r] = 0.0f;
                c = __builtin_amdgcn_mfma_f32_32x32x16_bf16(af, bf, c, 0, 0, 0);
                float m = c[0];
                #pragma unroll
                for (int r = 1; r < 16; ++r) m = fmaxf(m, c[r]);
                m = fmaxf(m, __shfl_xor(m, 32));
                float Z = 0.0f;
                #pragma unroll
                for (int r = 0; r < 16; ++r) { c[r] = __expf(c[r] - m); Z += c[r]; }
                Z += __shfl_xor(Z, 32);
                float rZ = (1.0f / 32.0f) / Z;
                #pragma unroll
                for (int g = 0; g < 4; ++g) {
                    int tb = 8 * g + 4 * h5;
                    int2v wv;
                    wv.x = pack_bf16_trunc(c[4 * g] * rZ, c[4 * g + 1] * rZ);
                    wv.y = pack_bf16_trunc(c[4 * g + 2] * rZ, c[4 * g + 3] * rZ);
                    *(int2v*)&att2[h][scol][tb] = wv;
                }
            }
        }
        __syncthreads();

        // ---- Phase D: abar[h][t] = sum_s att2 (mean folded into rZ) ----
        if (tid < 192) {
            const int h = tid >> 5, t = tid & 31;
            float sum = 0.0f;
            #pragma unroll
            for (int s = 0; s < 32; ++s)
                sum += bf16s_to_f((unsigned short)att2[h][s][t]);
            abar[h][t] = sum;
        }
        __syncthreads();

        // ---- Phase E: obar ----
        if (tid < 240) {
            const int he = tid >> 3, tq = tid & 7;
            const int h = he / 5, e = he - 5 * h;
            f32x4 av = *(const f32x4*)&abar[h][tq * 4];
            f32x4 vv = *(const f32x4*)&vT[h][e][tq * 4];
            float part = av.x * vv.x + av.y * vv.y + av.z * vv.z + av.w * vv.w;
            part += __shfl_down(part, 4, 8);
            part += __shfl_down(part, 2, 8);
            part += __shfl_down(part, 1, 8);
            if (tq == 0) obar[he] = part;
        }
        __syncthreads();

        // ---- Phase F: h1 = obar @ ow^T + ob ----
        if (tid < 240) {
            const int d = tid >> 3, jq = tid & 7;
            f32x4 ov = *(const f32x4*)&obar[jq * 4];
            float part = 0.0f;
            #pragma unroll
            for (int i = 0; i < 4; ++i) {
                int j = jq * 4 + i;
                if (j < 30) part = fmaf(ov[i], ow[d * 30 + j], part);
            }
            part += __shfl_down(part, 4, 8);
            part += __shfl_down(part, 2, 8);
            part += __shfl_down(part, 1, 8);
            if (jq == 0) h1out[pair * 30 + d] = part + ob[d];
        }
    }
}

// ---------------------------------------------------------------------------
// Kernel 2: first-hop layer (S=17 padded to 32, masked) + fused MLP.
// ---------------------------------------------------------------------------
__global__ __launch_bounds__(256, 4) void gl1_mlp_kernel(
    const float* __restrict__ h1, const float* __restrict__ self_feat,
    const float* __restrict__ lw, const float* __restrict__ lb,
    const float* __restrict__ iw, const float* __restrict__ ib,
    const float* __restrict__ ow, const float* __restrict__ ob,
    const float* __restrict__ cw1, const float* __restrict__ cb1,
    const float* __restrict__ cw2, const float* __restrict__ cb2,
    const float* __restrict__ cw3, const float* __restrict__ cb3,
    float* __restrict__ out)
{
    __shared__ short y_lds[32][40];
    __shared__ short qmf[6][33][8];
    __shared__ short kmf[6][33][8];
    __shared__ float vT[6][5][36];
    __shared__ short att2[6][32][40];
    __shared__ float abar[6][32];
    __shared__ float obar[32];
    __shared__ float embb[32];
    __shared__ float hb1[64];
    __shared__ float hb2[64];
    __shared__ float lg[2];

    const int tid  = threadIdx.x;
    const int lane = tid & 63;
    const int w    = tid >> 6;
    const int l15  = lane & 15;
    const int lq   = lane >> 4;
    const int h5   = lane >> 5;
    const int scol = lane & 31;
    const int rowz = (lane < 32) ? scol : 32;

    for (int i = tid; i < (6 * 33 * 8) / 2; i += 256) {
        ((int*)qmf)[i] = 0; ((int*)kmf)[i] = 0;
    }
    if (tid < 2) obar[30 + tid] = 0.0f;

    const int di = w & 1, si = w >> 1;
    short8 blw; float lbv;
    {
        int d = di * 16 + l15;
        #pragma unroll
        for (int i = 0; i < 8; ++i) {
            int k = lq * 8 + i;
            blw[i] = f2bf((d < 30 && k < 30) ? lw[d * 30 + k] : 0.0f);
        }
        lbv = (d < 30) ? lb[d] : 0.0f;
    }
    const int jtA = (3 * w) >> 1, jtB = (3 * w + 2) >> 1;
    short8 biwA, biwB; float ibvA, ibvB;
    {
        int jA = jtA * 16 + l15, jB = jtB * 16 + l15;
        #pragma unroll
        for (int i = 0; i < 8; ++i) {
            int k = lq * 8 + i;
            biwA[i] = f2bf((jA < 90 && k < 30) ? iw[jA * 30 + k] : 0.0f);
            biwB[i] = f2bf((jB < 90 && k < 30) ? iw[jB * 30 + k] : 0.0f);
        }
        ibvA = (jA < 90) ? ib[jA] : 0.0f;
        ibvB = (jB < 90) ? ib[jB] : 0.0f;
    }
    __syncthreads();

    for (int p = 0; p < NP1; ++p) {
        const long node = (long)blockIdx.x * NP1 + p;
        const float* h1p = h1 + node * 480;
        const float* sfp = self_feat + node * 30;

        // ---- Phase A: rows 0..15 = h1, row 16 = self_feat, rest padding ----
        {
            short8 af;
            if (si == 0) {
                int s = l15;
                #pragma unroll
                for (int i = 0; i < 8; ++i) {
                    int k = lq * 8 + i;
                    af[i] = f2bf((k < 30) ? h1p[s * 30 + k] : 0.0f);
                }
            } else {
                #pragma unroll
                for (int i = 0; i < 8; ++i) {
                    int k = lq * 8 + i;
                    af[i] = (l15 == 0 && k < 30) ? f2bf(sfp[k]) : (short)0;
                }
            }
            f32x4 c = {0.0f, 0.0f, 0.0f, 0.0f};
            c = __builtin_amdgcn_mfma_f32_16x16x32_bf16(af, blw, c, 0, 0, 0);
            #pragma unroll
            for (int r = 0; r < 4; ++r) {
                float yv = c[r] + lbv;
                yv = LRELU(yv);
                y_lds[si * 16 + lq * 4 + r][di * 16 + l15] = f2bf(yv);
            }
        }
        __syncthreads();

        // ---- Phase B ----
        {
            short8 a0 = *(const short8*)&y_lds[l15][lq * 8];
            short8 a1 = *(const short8*)&y_lds[16 + l15][lq * 8];
            #pragma unroll
            for (int t = 0; t < 3; ++t) {
                int T = 3 * w + t, jt = T >> 1, si_ = T & 1;
                short8 a = si_ ? a1 : a0;
                short8 b = (jt == jtA) ? biwA : biwB;
                float ibv = (jt == jtA) ? ibvA : ibvB;
                f32x4 c = {0.0f, 0.0f, 0.0f, 0.0f};
                c = __builtin_amdgcn_mfma_f32_16x16x32_bf16(a, b, c, 0, 0, 0);
                int j = jt * 16 + l15;
                int s0 = si_ * 16 + lq * 4;
                if (j < 30) {
                    int h = j / 5, e = j - 5 * h;
                    #pragma unroll
                    for (int r = 0; r < 4; ++r)
                        qmf[h][s0 + r][e] = f2bf(c[r] + ibv);
                } else if (j < 60) {
                    int jj = j - 30; int h = jj / 5, e = jj - 5 * h;
                    #pragma unroll
                    for (int r = 0; r < 4; ++r)
                        kmf[h][s0 + r][e] = f2bf((c[r] + ibv) * RS5);
                } else if (j < 90) {
                    int jj = j - 60; int h = jj / 5, e = jj - 5 * h;
                    #pragma unroll
                    for (int r = 0; r < 4; ++r)
                        vT[h][e][s0 + r] = c[r] + ibv;
                }
            }
        }
        __syncthreads();

        // ---- Phase C: MFMA scores + masked softmax (valid t < 17) ----
        if (w < 3) {
            #pragma unroll
            for (int hh = 0; hh < 2; ++hh) {
                const int h = 2 * w + hh;
                short8 af = *(const short8*)&kmf[h][rowz][0];
                short8 bf = *(const short8*)&qmf[h][rowz][0];
                f32x16 c;
                #pragma unroll
                for (int r = 0; r < 16; ++r) c[r] = 0.0f;
                c = __builtin_amdgcn_mfma_f32_32x32x16_bf16(af, bf, c, 0, 0, 0);
                #pragma unroll
                for (int r = 0; r < 16; ++r) {
                    int tr = (r & 3) + 8 * (r >> 2) + 4 * h5;
                    c[r] = (tr < 17) ? c[r] : -1e30f;
                }
                float m = c[0];
                #pragma unroll
                for (int r = 1; r < 16; ++r) m = fmaxf(m, c[r]);
                m = fmaxf(m, __shfl_xor(m, 32));
                float Z = 0.0f;
                #pragma unroll
                for (int r = 0; r < 16; ++r) { c[r] = __expf(c[r] - m); Z += c[r]; }
                Z += __shfl_xor(Z, 32);
                float rZ = (1.0f / 17.0f) / Z;
                #pragma unroll
                for (int g = 0; g < 4; ++g) {
                    int tb = 8 * g + 4 * h5;
                    int2v wv;
                    wv.x = pack_bf16_trunc(c[4 * g] * rZ, c[4 * g + 1] * rZ);
                    wv.y = pack_bf16_trunc(c[4 * g + 2] * rZ, c[4 * g + 3] * rZ);
                    *(int2v*)&att2[h][scol][tb] = wv;
                }
            }
        }
        __syncthreads();

        // ---- Phase D: abar over valid s < 17 ----
        if (tid < 192) {
            const int h = tid >> 5, t = tid & 31;
            float sum = 0.0f;
            #pragma unroll
            for (int s = 0; s < 17; ++s)
                sum += bf16s_to_f((unsigned short)att2[h][s][t]);
            abar[h][t] = sum;
        }
        __syncthreads();

        // ---- Phase E ----
        if (tid < 240) {
            const int he = tid >> 3, tq = tid & 7;
            const int h = he / 5, e = he - 5 * h;
            f32x4 av = *(const f32x4*)&abar[h][tq * 4];
            f32x4 vv = *(const f32x4*)&vT[h][e][tq * 4];
            float part = av.x * vv.x + av.y * vv.y + av.z * vv.z + av.w * vv.w;
            part += __shfl_down(part, 4, 8);
            part += __shfl_down(part, 2, 8);
            part += __shfl_down(part, 1, 8);
            if (tq == 0) obar[he] = part;
        }
        __syncthreads();

        // ---- Phase F: emb ----
        if (tid < 240) {
            const int d = tid >> 3, jq = tid & 7;
            f32x4 ov = *(const f32x4*)&obar[jq * 4];
            float part = 0.0f;
            #pragma unroll
            for (int i = 0; i < 4; ++i) {
                int j = jq * 4 + i;
                if (j < 30) part = fmaf(ov[i], ow[d * 30 + j], part);
            }
            part += __shfl_down(part, 4, 8);
            part += __shfl_down(part, 2, 8);
            part += __shfl_down(part, 1, 8);
            if (jq == 0) embb[d] = part + ob[d];
        }
        __syncthreads();

        // ---- MLP 30 -> 64 -> 64 -> 2 + softmax ----
        {
            const int o = tid >> 2, kq = tid & 3;
            float part = 0.0f;
            #pragma unroll
            for (int i = 0; i < 8; ++i) {
                int k = kq * 8 + i;
                if (k < 30) part = fmaf(embb[k], cw1[o * 30 + k], part);
            }
            part += __shfl_down(part, 2, 4);
            part += __shfl_down(part, 1, 4);
            if (kq == 0) hb1[o] = LRELU(part + cb1[o]);
        }
        __syncthreads();
        {
            const int o = tid >> 2, kq = tid & 3;
            float part = 0.0f;
            #pragma unroll
            for (int i = 0; i < 16; ++i) {
                int k = kq * 16 + i;
                part = fmaf(hb1[k], cw2[o * 64 + k], part);
            }
            part += __shfl_down(part, 2, 4);
            part += __shfl_down(part, 1, 4);
            if (kq == 0) hb2[o] = LRELU(part + cb2[o]);
        }
        __syncthreads();
        if (tid < 128) {
            const int c = tid >> 6, k = tid & 63;
            float part = hb2[k] * cw3[c * 64 + k];
            part += __shfl_down(part, 32);
            part += __shfl_down(part, 16);
            part += __shfl_down(part, 8);
            part += __shfl_down(part, 4);
            part += __shfl_down(part, 2);
            part += __shfl_down(part, 1);
            if (k == 0) lg[c] = part + cb3[c];
        }
        __syncthreads();
        if (tid < 2) {
            float m = fmaxf(lg[0], lg[1]);
            float e0 = __expf(lg[0] - m), e1 = __expf(lg[1] - m);
            float pr = ((tid == 0) ? e0 : e1) / (e0 + e1);
            out[node * 2 + tid] = pr;
        }
        __syncthreads();
    }
}

extern "C" void kernel_launch(void* const* d_in, const int* in_sizes, int n_in,
                              void* d_out, int out_size, void* d_ws, size_t ws_size,
                              hipStream_t stream)
{
    const float* x2        = (const float*)d_in[0];
    const float* self_feat = (const float*)d_in[1];
    const float* lin_w2 = (const float*)d_in[2];
    const float* lin_b2 = (const float*)d_in[3];
    const float* in_w2  = (const float*)d_in[4];
    const float* in_b2  = (const float*)d_in[5];
    const float* out_w2 = (const float*)d_in[6];
    const float* out_b2 = (const float*)d_in[7];
    const float* lin_w1 = (const float*)d_in[8];
    const float* lin_b1 = (const float*)d_in[9];
    const float* in_w1  = (const float*)d_in[10];
    const float* in_b1  = (const float*)d_in[11];
    const float* out_w1 = (const float*)d_in[12];
    const float* out_b1 = (const float*)d_in[13];
    const float* cw1 = (const float*)d_in[14];
    const float* cb1 = (const float*)d_in[15];
    const float* cw2 = (const float*)d_in[16];
    const float* cb2 = (const float*)d_in[17];
    const float* cw3 = (const float*)d_in[18];
    const float* cb3 = (const float*)d_in[19];
    float* outp = (float*)d_out;

    float* h1 = (float*)d_ws;   // 65536 * 30 floats = 7.86 MB

    gl2_kernel<<<(4096 * 16) / PAIRS, 256, 0, stream>>>(
        x2, lin_w2, lin_b2, in_w2, in_b2, out_w2, out_b2, h1);

    gl1_mlp_kernel<<<4096 / NP1, 256, 0, stream>>>(
        h1, self_feat, lin_w1, lin_b1, in_w1, in_b1, out_w1, out_b1,
        cw1, cb1, cw2, cb2, cw3, cb3, outp);
}